// Round 2
// baseline (27629.230 us; speedup 1.0000x reference)
//
#include <hip/hip_runtime.h>
#include <math.h>

#define NOPS 7
#define KITERS 3
#define NBLK 31   // 31 perm-blocks x 4 masks = 124 rounds = exactly 4 full sweeps

// lane-xor exchange: M=1,2 via DPP quad_perm (VALU pipe), M=4,8 via ds_swizzle (32-lane groups)
template<int M> __device__ __forceinline__ float xshuf(float x);
template<> __device__ __forceinline__ float xshuf<1>(float x) {
    return __int_as_float(__builtin_amdgcn_mov_dpp(__float_as_int(x), 0xB1, 0xF, 0xF, true));
}
template<> __device__ __forceinline__ float xshuf<2>(float x) {
    return __int_as_float(__builtin_amdgcn_mov_dpp(__float_as_int(x), 0x4E, 0xF, 0xF, true));
}
template<> __device__ __forceinline__ float xshuf<4>(float x) {
    return __int_as_float(__builtin_amdgcn_ds_swizzle(__float_as_int(x), (4 << 10) | 0x1F));
}
template<> __device__ __forceinline__ float xshuf<8>(float x) {
    return __int_as_float(__builtin_amdgcn_ds_swizzle(__float_as_int(x), (8 << 10) | 0x1F));
}

// One Jacobi round, pairing {x, x^M}. Lane (il, c=lane>>5) holds:
//   a[j] = M[il][il ^ (16c+j)]  (xor-aligned columns, chunk split by bit4)
//   v[j] = V[il][16c+j]         (plain column slots)
template<int M>
__device__ __forceinline__ void jround(float (&a)[16], float (&v)[16], float2* ct,
                                       const int il, const int lane, const int fKb) {
    const int fil = (il & (M - 1)) | ((il >> 1) & ~(M - 1));   // 4-bit pair id of row il
    const float dq  = xshuf<M>(a[0]);    // partner diagonal (valid on chunk-0 lanes)
    const float apq = a[M];
    float cc = 1.f, ss = 0.f;
    if (fabsf(apq) > 1e-12f) {
        const float th = (dq - a[0]) / (2.f * apq);
        const float t  = copysignf(1.f, th) / (fabsf(th) + sqrtf(1.f + th * th));
        cc = rsqrtf(1.f + t * t);
        ss = t * cc;
    }
    if ((lane & (32 | M)) == 0) ct[fil] = make_float2(cc, ss);   // chunk0 p-role lanes
    __syncthreads();
    const float2 me = ct[fil];
    const float sg = (il & M) ? 1.f : -1.f;
    const float c0 = me.x, s0 = sg * me.y;
    // column rotations on a (pairs (j, j^M) = cols (il^K, il^K^M)) and on v (slot pair)
    #pragma unroll
    for (int j = 0; j < 16; ++j) {
        if (j & M) continue;
        const int fj = (j & (M - 1)) | ((j >> 1) & ~(M - 1));   // 3-bit compress
        const float2 cs = ct[fil ^ (fj | fKb)];
        const float sl = sg * cs.y;
        const float ak = a[j], am = a[j ^ M];
        a[j]     = fmaf( sl, am, cs.x * ak);
        a[j ^ M] = fmaf(-sl, ak, cs.x * am);
        const float2 cu = ct[fj | fKb];
        const float vk = v[j], vm = v[j ^ M];
        v[j]     = fmaf(-cu.y, vm, cu.x * vk);
        v[j ^ M] = fmaf( cu.y, vk, cu.x * vm);
    }
    // row mix: own' = c0*own + s0*partner (partner stores my col il^K at slot K^M)
    #pragma unroll
    for (int j = 0; j < 16; ++j) {
        if (j & M) continue;
        const float r1 = xshuf<M>(a[j ^ M]);
        const float r2 = xshuf<M>(a[j]);
        a[j]     = fmaf(s0, r1, c0 * a[j]);
        a[j ^ M] = fmaf(s0, r2, c0 * a[j ^ M]);
    }
}

__global__ __launch_bounds__(64, 4)
void karcher_kernel(const float* __restrict__ spds, const float* __restrict__ alphas,
                    float* __restrict__ out, int Mtot) {
    __shared__ __align__(16) float XI[1024];   // Xih (then E / T2), column-major [t][r]
    __shared__ __align__(16) float SC[1024];   // scratch stage, column-major
    __shared__ float2 CT[16];
    __shared__ float FDA[32];
    __shared__ float FDB[32];
    __shared__ float WS[8];

    const int lane  = threadIdx.x;
    const int il    = lane & 31;        // row
    const int cbit  = lane >> 5;        // column chunk
    const int cbase = cbit << 4;
    const int fKb   = cbit << 3;
    const int c13   = cbit ? 13 : 0;    // L4(16) = 13
    const int mat   = blockIdx.x;
    const bool rr   = (il < 30);

    if (lane == 0) {
        float aa[NOPS], mx = -1e30f, sum = 0.f;
        #pragma unroll
        for (int o = 0; o < NOPS; ++o) { aa[o] = alphas[o]; mx = fmaxf(mx, aa[o]); }
        #pragma unroll
        for (int o = 0; o < NOPS; ++o) { aa[o] = expf(aa[o] - mx); sum += aa[o]; }
        #pragma unroll
        for (int o = 0; o < NOPS; ++o) WS[o] = aa[o] / sum;
    }

    int l4row = il;   // L^4 of own row (companion matrix of x^5+x^2+1)
    #pragma unroll
    for (int i = 0; i < 4; ++i) l4row = ((l4row << 1) & 31) ^ ((l4row & 16) ? 5 : 0);

    const size_t ostr = (size_t)Mtot * 900;
    const float* Abase = spds + (size_t)mat * 900 + (size_t)il * 30 + cbase;
    float* orow = out + (size_t)mat * 900 + (size_t)il * 30 + cbase;

    auto stage16 = [&](float* buf, const float (&r)[16]) {   // buf[t*32+il] = row il, col t
        #pragma unroll
        for (int j = 0; j < 16; ++j) buf[((cbase + j) << 5) + il] = r[j];
    };
    auto xload16 = [&](const float* buf, float (&a)[16]) {   // a[j] = M[il][il^(16c+j)]
        #pragma unroll
        for (int j = 0; j < 16; ++j) a[j] = buf[((il ^ (cbase + j)) << 5) + il];
    };
    auto perm4 = [&](float (&a)[16], float (&v)[16]) {       // relabel by L^4 via SC bounce
        constexpr int L4T[16] = {0,16,5,21,10,26,15,31,20,4,17,1,30,14,27,11};
        #pragma unroll
        for (int j = 0; j < 16; ++j) SC[((cbase + j) << 5) + il] = a[j];
        __syncthreads();
        #pragma unroll
        for (int j = 0; j < 16; ++j) a[j] = SC[((L4T[j] ^ c13) << 5) + l4row];
        __syncthreads();
        #pragma unroll
        for (int j = 0; j < 16; ++j) SC[((cbase + j) << 5) + il] = v[j];
        __syncthreads();
        #pragma unroll
        for (int j = 0; j < 16; ++j) v[j] = SC[((L4T[j] ^ c13) << 5) + il];
        __syncthreads();
    };
    auto jacobi = [&](float (&a)[16], float (&v)[16]) {
        #pragma unroll
        for (int j = 0; j < 16; ++j) v[j] = (cbase + j == il) ? 1.f : 0.f;
        #pragma unroll 1
        for (int b = 0; b < NBLK; ++b) {
            jround<1>(a, v, CT, il, lane, fKb);
            jround<2>(a, v, CT, il, lane, fKb);
            jround<4>(a, v, CT, il, lane, fKb);
            jround<8>(a, v, CT, il, lane, fKb);
            perm4(a, v);
        }
    };
    auto loadA = [&](const float* Ao, float (&r)[16]) {      // own 16-col slice of a row
        #pragma unroll
        for (int u = 0; u < 7; ++u) {
            const float2 p = *(const float2*)(Ao + 2 * u);
            r[2 * u] = p.x; r[2 * u + 1] = p.y;
        }
        if (cbit == 0) {
            const float2 p = *(const float2*)(Ao + 14);
            r[14] = p.x; r[15] = p.y;
        }
    };
    auto fma16 = [&](const float* buf, const int k, const float c, float (&acc)[16]) {
        const float4* bp = (const float4*)(buf + (k << 5) + cbase);
        #pragma unroll
        for (int q = 0; q < 4; ++q) {
            const float4 b = bp[q];
            acc[4*q+0] = fmaf(c, b.x, acc[4*q+0]);
            acc[4*q+1] = fmaf(c, b.y, acc[4*q+1]);
            acc[4*q+2] = fmaf(c, b.z, acc[4*q+2]);
            acc[4*q+3] = fmaf(c, b.w, acc[4*q+3]);
        }
    };

    __syncthreads();   // WS visible

    // ---- X = sum_o w_o A_o (padding rows/cols stay exactly 0) ----
    float X[16];
    #pragma unroll
    for (int j = 0; j < 16; ++j) X[j] = 0.f;
    if (rr) {
        #pragma unroll 1
        for (int o = 0; o < NOPS; ++o) {
            const float wo = WS[o];
            float r[16];
            #pragma unroll
            for (int j = 0; j < 16; ++j) r[j] = 0.f;
            loadA(Abase + (size_t)o * ostr, r);
            #pragma unroll
            for (int j = 0; j < 16; ++j) X[j] = fmaf(wo, r[j], X[j]);
        }
    }

    float xh[16], Lacc[16];

    #pragma unroll 1
    for (int it = 0; it < KITERS; ++it) {
        // ---- eigh(X) ----
        __syncthreads();
        stage16(SC, X);
        __syncthreads();
        float a1[16], v1[16];
        xload16(SC, a1);
        jacobi(a1, v1);
        if (lane < 32) {
            const float lam = fmaxf(a1[0], 1e-8f);
            const float sq = sqrtf(lam);
            FDA[il] = sq;
            FDB[il] = 1.f / sq;
        }
        __syncthreads();
        stage16(SC, v1);
        __syncthreads();
        // ---- Xh (regs), Xih (-> XI) ----
        float xi[16];
        #pragma unroll
        for (int j = 0; j < 16; ++j) { xh[j] = 0.f; xi[j] = 0.f; }
        #pragma unroll 2
        for (int k = 0; k < 30; ++k) {
            const float vk = SC[(k << 5) + il];   // V[il][k]
            const float c1 = FDA[k] * vk;
            const float c2 = FDB[k] * vk;
            const float4* bp = (const float4*)(SC + (k << 5) + cbase);   // V[t][k]
            #pragma unroll
            for (int q = 0; q < 4; ++q) {
                const float4 b = bp[q];
                xh[4*q+0] = fmaf(c1, b.x, xh[4*q+0]); xi[4*q+0] = fmaf(c2, b.x, xi[4*q+0]);
                xh[4*q+1] = fmaf(c1, b.y, xh[4*q+1]); xi[4*q+1] = fmaf(c2, b.y, xi[4*q+1]);
                xh[4*q+2] = fmaf(c1, b.z, xh[4*q+2]); xi[4*q+2] = fmaf(c2, b.z, xi[4*q+2]);
                xh[4*q+3] = fmaf(c1, b.w, xh[4*q+3]); xi[4*q+3] = fmaf(c2, b.w, xi[4*q+3]);
            }
        }
        __syncthreads();
        stage16(XI, xi);
        #pragma unroll
        for (int j = 0; j < 16; ++j) Lacc[j] = 0.f;

        // ---- op loop: Lacc += w_o logm(Xih A_o Xih) ----
        #pragma unroll 1
        for (int o = 0; o < NOPS; ++o) {
            float ar[16];
            #pragma unroll
            for (int j = 0; j < 16; ++j) ar[j] = 0.f;
            if (rr) loadA(Abase + (size_t)o * ostr, ar);
            __syncthreads();
            stage16(SC, ar);
            __syncthreads();
            float T[16];
            #pragma unroll
            for (int j = 0; j < 16; ++j) T[j] = 0.f;
            #pragma unroll 2
            for (int k = 0; k < 30; ++k)          // T = Xih * A   (A symmetric)
                fma16(SC, k, XI[(k << 5) + il], T);
            __syncthreads();
            stage16(SC, T);                        // A dead
            __syncthreads();
            float md[16];
            #pragma unroll
            for (int j = 0; j < 16; ++j) md[j] = 0.f;
            #pragma unroll 2
            for (int k = 0; k < 30; ++k)          // mid = T * Xih (Xih symmetric)
                fma16(XI, k, SC[(k << 5) + il], md);
            __syncthreads();
            stage16(SC, md);
            __syncthreads();
            float a2[16], v2[16];
            xload16(SC, a2);
            jacobi(a2, v2);
            if (lane < 32) FDA[il] = logf(fmaxf(a2[0], 1e-8f));
            __syncthreads();
            stage16(SC, v2);
            __syncthreads();
            const float wo = WS[o];
            #pragma unroll 2
            for (int k = 0; k < 30; ++k)          // Lacc += wo * V log(L) V^T
                fma16(SC, k, wo * FDA[k] * SC[(k << 5) + il], Lacc);
        }

        // ---- E = expm(L); X' = Xh E Xh ----
        __syncthreads();
        stage16(SC, Lacc);
        __syncthreads();
        float a3[16], v3[16];
        xload16(SC, a3);
        jacobi(a3, v3);
        if (lane < 32) FDA[il] = expf(fmaxf(a3[0], 1e-8f));   // reference clamps before exp
        __syncthreads();
        stage16(SC, v3);
        __syncthreads();
        float E[16];
        #pragma unroll
        for (int j = 0; j < 16; ++j) E[j] = 0.f;
        #pragma unroll 2
        for (int k = 0; k < 30; ++k)
            fma16(SC, k, FDA[k] * SC[(k << 5) + il], E);
        __syncthreads();
        stage16(XI, E);        // XI = E (Xih dead)
        stage16(SC, xh);       // SC = Xh (V3 dead; in-wave order safe)
        __syncthreads();
        float T2[16];
        #pragma unroll
        for (int j = 0; j < 16; ++j) T2[j] = 0.f;
        #pragma unroll 2
        for (int k = 0; k < 30; ++k)              // T2 = Xh * E (E symmetric)
            fma16(XI, k, SC[(k << 5) + il], T2);
        __syncthreads();
        stage16(XI, T2);       // E dead
        __syncthreads();
        #pragma unroll
        for (int j = 0; j < 16; ++j) X[j] = 0.f;
        #pragma unroll 2
        for (int k = 0; k < 30; ++k)              // X' = T2 * Xh (Xh symmetric)
            fma16(SC, k, XI[(k << 5) + il], X);
    }

    if (rr) {
        #pragma unroll
        for (int u = 0; u < 7; ++u)
            *(float2*)(orow + 2 * u) = make_float2(X[2*u], X[2*u+1]);
        if (cbit == 0)
            *(float2*)(orow + 14) = make_float2(X[14], X[15]);
    }
}

extern "C" void kernel_launch(void* const* d_in, const int* in_sizes, int n_in,
                              void* d_out, int out_size, void* d_ws, size_t ws_size,
                              hipStream_t stream) {
    const float* spds   = (const float*)d_in[0];
    const float* alphas = (const float*)d_in[1];
    float* out = (float*)d_out;
    const int Mtot = in_sizes[0] / (NOPS * 900);   // 8192
    karcher_kernel<<<dim3(Mtot), dim3(64), 0, stream>>>(spds, alphas, out, Mtot);
}

// Round 3
// 9388.429 us; speedup vs baseline: 2.9429x; 2.9429x over previous
//
#include <hip/hip_runtime.h>
#include <math.h>

#define NOPS 7
#define KITERS 3
#define NBLK 31   // 31 perm-blocks x 4 masks = 124 rounds = exactly 4 full sweeps

// lane-xor exchange: M=1,2 via DPP quad_perm (VALU pipe), M=4,8 via ds_swizzle (32-lane groups)
template<int M> __device__ __forceinline__ float xshuf(float x);
template<> __device__ __forceinline__ float xshuf<1>(float x) {
    return __int_as_float(__builtin_amdgcn_mov_dpp(__float_as_int(x), 0xB1, 0xF, 0xF, true));
}
template<> __device__ __forceinline__ float xshuf<2>(float x) {
    return __int_as_float(__builtin_amdgcn_mov_dpp(__float_as_int(x), 0x4E, 0xF, 0xF, true));
}
template<> __device__ __forceinline__ float xshuf<4>(float x) {
    return __int_as_float(__builtin_amdgcn_ds_swizzle(__float_as_int(x), (4 << 10) | 0x1F));
}
template<> __device__ __forceinline__ float xshuf<8>(float x) {
    return __int_as_float(__builtin_amdgcn_ds_swizzle(__float_as_int(x), (8 << 10) | 0x1F));
}

// One Jacobi round, pairing {x, x^M}. Lane (il, c=lane>>5) holds:
//   a[j] = M[il][il ^ (16c+j)]  (xor-aligned columns, chunk split by bit4)
//   v[j] = V[il][16c+j]         (plain column slots)
template<int M>
__device__ __forceinline__ void jround(float (&a)[16], float (&v)[16], float2* ct,
                                       const int il, const int lane, const int fKb) {
    const int fil = (il & (M - 1)) | ((il >> 1) & ~(M - 1));   // 4-bit pair id of row il
    const float dq  = xshuf<M>(a[0]);    // partner diagonal
    const float apq = a[M];
    float cc = 1.f, ss = 0.f;
    if (fabsf(apq) > 1e-12f) {
        const float th = (dq - a[0]) / (2.f * apq);
        const float t  = copysignf(1.f, th) / (fabsf(th) + sqrtf(1.f + th * th));
        cc = rsqrtf(1.f + t * t);
        ss = t * cc;
    }
    if ((lane & (32 | M)) == 0) ct[fil] = make_float2(cc, ss);   // chunk0 p-role lanes
    __syncthreads();
    const float2 me = ct[fil];
    const float sg = (il & M) ? 1.f : -1.f;
    const float c0 = me.x, s0 = sg * me.y;
    // column rotations on a (pairs (j, j^M) = cols (il^K, il^K^M)) and on v (slot pair)
    #pragma unroll
    for (int j = 0; j < 16; ++j) {
        if (j & M) continue;
        const int fj = (j & (M - 1)) | ((j >> 1) & ~(M - 1));   // 3-bit compress
        const float2 cs = ct[fil ^ (fj | fKb)];
        const float sl = sg * cs.y;
        const float ak = a[j], am = a[j ^ M];
        a[j]     = fmaf( sl, am, cs.x * ak);
        a[j ^ M] = fmaf(-sl, ak, cs.x * am);
        const float2 cu = ct[fj | fKb];
        const float vk = v[j], vm = v[j ^ M];
        v[j]     = fmaf(-cu.y, vm, cu.x * vk);
        v[j ^ M] = fmaf( cu.y, vk, cu.x * vm);
    }
    // row mix: own' = c0*own + s0*partner (partner stores my col il^K at slot K^M)
    #pragma unroll
    for (int j = 0; j < 16; ++j) {
        if (j & M) continue;
        const float r1 = xshuf<M>(a[j ^ M]);
        const float r2 = xshuf<M>(a[j]);
        a[j]     = fmaf(s0, r1, c0 * a[j]);
        a[j ^ M] = fmaf(s0, r2, c0 * a[j ^ M]);
    }
}

__global__ __launch_bounds__(64)
void karcher_kernel(const float* __restrict__ spds, const float* __restrict__ alphas,
                    float* __restrict__ out, int Mtot) {
    __shared__ __align__(16) float XI[1024];   // Xih (then E / T2), column-major [t][r]
    __shared__ __align__(16) float SC[1024];   // scratch stage, column-major
    __shared__ float2 CT[16];
    __shared__ float FDA[32];
    __shared__ float FDB[32];
    __shared__ float WS[8];

    const int lane  = threadIdx.x;
    const int il    = lane & 31;        // row
    const int cbit  = lane >> 5;        // column chunk
    const int cbase = cbit << 4;
    const int fKb   = cbit << 3;
    const int c13   = cbit ? 13 : 0;    // L4(16) = 13
    const int mat   = blockIdx.x;
    const bool rr   = (il < 30);

    if (lane == 0) {
        float aa[NOPS], mx = -1e30f, sum = 0.f;
        #pragma unroll
        for (int o = 0; o < NOPS; ++o) { aa[o] = alphas[o]; mx = fmaxf(mx, aa[o]); }
        #pragma unroll
        for (int o = 0; o < NOPS; ++o) { aa[o] = expf(aa[o] - mx); sum += aa[o]; }
        #pragma unroll
        for (int o = 0; o < NOPS; ++o) WS[o] = aa[o] / sum;
    }

    int l4row = il;   // L^4 of own row (companion matrix of x^5+x^2+1)
    #pragma unroll
    for (int i = 0; i < 4; ++i) l4row = ((l4row << 1) & 31) ^ ((l4row & 16) ? 5 : 0);

    const size_t ostr = (size_t)Mtot * 900;
    const float* Abase = spds + (size_t)mat * 900 + (size_t)il * 30 + cbase;
    float* orow = out + (size_t)mat * 900 + (size_t)il * 30 + cbase;   // park + final output

    auto stage16 = [&](float* buf, const float (&r)[16]) {   // buf[t*32+il] = row il, col t
        #pragma unroll
        for (int j = 0; j < 16; ++j) buf[((cbase + j) << 5) + il] = r[j];
    };
    auto xload16 = [&](const float* buf, float (&a)[16]) {   // a[j] = M[il][il^(16c+j)]
        #pragma unroll
        for (int j = 0; j < 16; ++j) a[j] = buf[((il ^ (cbase + j)) << 5) + il];
    };
    auto perm4 = [&](float (&a)[16], float (&v)[16]) {       // relabel by L^4 via SC bounce
        constexpr int L4T[16] = {0,16,5,21,10,26,15,31,20,4,17,1,30,14,27,11};
        #pragma unroll
        for (int j = 0; j < 16; ++j) SC[((cbase + j) << 5) + il] = a[j];
        __syncthreads();
        #pragma unroll
        for (int j = 0; j < 16; ++j) a[j] = SC[((L4T[j] ^ c13) << 5) + l4row];
        __syncthreads();
        #pragma unroll
        for (int j = 0; j < 16; ++j) SC[((cbase + j) << 5) + il] = v[j];
        __syncthreads();
        #pragma unroll
        for (int j = 0; j < 16; ++j) v[j] = SC[((L4T[j] ^ c13) << 5) + il];
        __syncthreads();
    };
    auto jacobi = [&](float (&a)[16], float (&v)[16]) {
        #pragma unroll
        for (int j = 0; j < 16; ++j) v[j] = (cbase + j == il) ? 1.f : 0.f;
        #pragma unroll 1
        for (int b = 0; b < NBLK; ++b) {
            jround<1>(a, v, CT, il, lane, fKb);
            jround<2>(a, v, CT, il, lane, fKb);
            jround<4>(a, v, CT, il, lane, fKb);
            jround<8>(a, v, CT, il, lane, fKb);
            perm4(a, v);
        }
    };
    auto loadA = [&](const float* Ao, float (&r)[16]) {      // own 16-col slice of a row
        #pragma unroll
        for (int u = 0; u < 7; ++u) {
            const float2 p = *(const float2*)(Ao + 2 * u);
            r[2 * u] = p.x; r[2 * u + 1] = p.y;
        }
        if (cbit == 0) {
            const float2 p = *(const float2*)(Ao + 14);
            r[14] = p.x; r[15] = p.y;
        }
    };
    auto fma16 = [&](const float* buf, const int k, const float c, float (&acc)[16]) {
        const float4* bp = (const float4*)(buf + (k << 5) + cbase);
        #pragma unroll
        for (int q = 0; q < 4; ++q) {
            const float4 b = bp[q];
            acc[4*q+0] = fmaf(c, b.x, acc[4*q+0]);
            acc[4*q+1] = fmaf(c, b.y, acc[4*q+1]);
            acc[4*q+2] = fmaf(c, b.z, acc[4*q+2]);
            acc[4*q+3] = fmaf(c, b.w, acc[4*q+3]);
        }
    };

    __syncthreads();   // WS visible

    // ---- X = sum_o w_o A_o (padding rows/cols stay exactly 0) ----
    float X[16];
    #pragma unroll
    for (int j = 0; j < 16; ++j) X[j] = 0.f;
    if (rr) {
        #pragma unroll 1
        for (int o = 0; o < NOPS; ++o) {
            const float wo = WS[o];
            float r[16];
            #pragma unroll
            for (int j = 0; j < 16; ++j) r[j] = 0.f;
            loadA(Abase + (size_t)o * ostr, r);
            #pragma unroll
            for (int j = 0; j < 16; ++j) X[j] = fmaf(wo, r[j], X[j]);
        }
    }

    float Lacc[16];

    #pragma unroll 1
    for (int it = 0; it < KITERS; ++it) {
        // ---- eigh(X) ----
        __syncthreads();
        stage16(SC, X);
        __syncthreads();
        float a1[16], v1[16];
        xload16(SC, a1);
        jacobi(a1, v1);
        if (lane < 32) {
            const float lam = fmaxf(a1[0], 1e-8f);
            const float sq = sqrtf(lam);
            FDA[il] = sq;
            FDB[il] = 1.f / sq;
        }
        __syncthreads();
        stage16(SC, v1);
        __syncthreads();
        // ---- Xh -> park in out[], Xih -> XI ----
        {
            float xh[16], xi[16];
            #pragma unroll
            for (int j = 0; j < 16; ++j) { xh[j] = 0.f; xi[j] = 0.f; }
            #pragma unroll 2
            for (int k = 0; k < 30; ++k) {
                const float vk = SC[(k << 5) + il];   // V[il][k]
                const float c1 = FDA[k] * vk;
                const float c2 = FDB[k] * vk;
                const float4* bp = (const float4*)(SC + (k << 5) + cbase);   // V[t][k]
                #pragma unroll
                for (int q = 0; q < 4; ++q) {
                    const float4 b = bp[q];
                    xh[4*q+0] = fmaf(c1, b.x, xh[4*q+0]); xi[4*q+0] = fmaf(c2, b.x, xi[4*q+0]);
                    xh[4*q+1] = fmaf(c1, b.y, xh[4*q+1]); xi[4*q+1] = fmaf(c2, b.y, xi[4*q+1]);
                    xh[4*q+2] = fmaf(c1, b.z, xh[4*q+2]); xi[4*q+2] = fmaf(c2, b.z, xi[4*q+2]);
                    xh[4*q+3] = fmaf(c1, b.w, xh[4*q+3]); xi[4*q+3] = fmaf(c2, b.w, xi[4*q+3]);
                }
            }
            if (rr) {   // park Xh row (each lane round-trips only its own slice)
                #pragma unroll
                for (int u = 0; u < 7; ++u)
                    *(float2*)(orow + 2 * u) = make_float2(xh[2*u], xh[2*u+1]);
                if (cbit == 0)
                    *(float2*)(orow + 14) = make_float2(xh[14], xh[15]);
            }
            __syncthreads();
            stage16(XI, xi);
        }
        #pragma unroll
        for (int j = 0; j < 16; ++j) Lacc[j] = 0.f;

        // ---- op loop: Lacc += w_o logm(Xih A_o Xih) ----
        #pragma unroll 1
        for (int o = 0; o < NOPS; ++o) {
            float ar[16];
            #pragma unroll
            for (int j = 0; j < 16; ++j) ar[j] = 0.f;
            if (rr) loadA(Abase + (size_t)o * ostr, ar);
            __syncthreads();
            stage16(SC, ar);
            __syncthreads();
            float T[16];
            #pragma unroll
            for (int j = 0; j < 16; ++j) T[j] = 0.f;
            #pragma unroll 2
            for (int k = 0; k < 30; ++k)          // T = Xih * A   (A symmetric)
                fma16(SC, k, XI[(k << 5) + il], T);
            __syncthreads();
            stage16(SC, T);                        // A dead
            __syncthreads();
            float md[16];
            #pragma unroll
            for (int j = 0; j < 16; ++j) md[j] = 0.f;
            #pragma unroll 2
            for (int k = 0; k < 30; ++k)          // mid = T * Xih (Xih symmetric)
                fma16(XI, k, SC[(k << 5) + il], md);
            __syncthreads();
            stage16(SC, md);
            __syncthreads();
            float a2[16], v2[16];
            xload16(SC, a2);
            jacobi(a2, v2);
            if (lane < 32) FDA[il] = logf(fmaxf(a2[0], 1e-8f));
            __syncthreads();
            stage16(SC, v2);
            __syncthreads();
            const float wo = WS[o];
            #pragma unroll 2
            for (int k = 0; k < 30; ++k)          // Lacc += wo * V log(L) V^T
                fma16(SC, k, wo * FDA[k] * SC[(k << 5) + il], Lacc);
        }

        // ---- E = expm(L); X' = Xh E Xh ----
        __syncthreads();
        stage16(SC, Lacc);
        __syncthreads();
        float a3[16], v3[16];
        xload16(SC, a3);
        jacobi(a3, v3);
        if (lane < 32) FDA[il] = expf(fmaxf(a3[0], 1e-8f));   // reference clamps before exp
        __syncthreads();
        stage16(SC, v3);
        __syncthreads();
        float E[16];
        #pragma unroll
        for (int j = 0; j < 16; ++j) E[j] = 0.f;
        #pragma unroll 2
        for (int k = 0; k < 30; ++k)
            fma16(SC, k, FDA[k] * SC[(k << 5) + il], E);
        // un-park Xh row slice
        float xr[16];
        #pragma unroll
        for (int j = 0; j < 16; ++j) xr[j] = 0.f;
        if (rr) loadA(orow, xr);
        __syncthreads();
        stage16(XI, E);        // XI = E (Xih dead)
        stage16(SC, xr);       // SC = Xh (v3 dead; single-wave order safe)
        __syncthreads();
        float T2[16];
        #pragma unroll
        for (int j = 0; j < 16; ++j) T2[j] = 0.f;
        #pragma unroll 2
        for (int k = 0; k < 30; ++k)              // T2 = Xh * E (E symmetric)
            fma16(XI, k, SC[(k << 5) + il], T2);
        __syncthreads();
        stage16(XI, T2);       // E dead
        __syncthreads();
        #pragma unroll
        for (int j = 0; j < 16; ++j) X[j] = 0.f;
        #pragma unroll 2
        for (int k = 0; k < 30; ++k)              // X' = T2 * Xh (Xh symmetric)
            fma16(SC, k, XI[(k << 5) + il], X);
    }

    if (rr) {
        #pragma unroll
        for (int u = 0; u < 7; ++u)
            *(float2*)(orow + 2 * u) = make_float2(X[2*u], X[2*u+1]);
        if (cbit == 0)
            *(float2*)(orow + 14) = make_float2(X[14], X[15]);
    }
}

extern "C" void kernel_launch(void* const* d_in, const int* in_sizes, int n_in,
                              void* d_out, int out_size, void* d_ws, size_t ws_size,
                              hipStream_t stream) {
    const float* spds   = (const float*)d_in[0];
    const float* alphas = (const float*)d_in[1];
    float* out = (float*)d_out;
    const int Mtot = in_sizes[0] / (NOPS * 900);   // 8192
    karcher_kernel<<<dim3(Mtot), dim3(64), 0, stream>>>(spds, alphas, out, Mtot);
}